// Round 6
// baseline (2451.190 us; speedup 1.0000x reference)
//
#include <hip/hip_runtime.h>
#include <cstdint>

#define NNODES 20000
#define NEDGES 320000
#define ETOT   340000   // NEDGES + NNODES self loops
#define TSTEPS 10
#define BCLF   4096
#define EMB    128
#define HC     512      // HEADS * EMB
#define NEG_SLOPE 0.2f

// CSR build: 64 dst sub-buckets per graph, packed records, LDS-staged fill
#define NSB    64
#define SBSPAN 313                                  // ceil(20000/64); 64*313 = 20032
#define PCAP   6912                                 // mean 5008 + 27 sigma
#define ECHUNK 2048
#define NCHUNKS ((NEDGES + ECHUNK - 1) / ECHUNK)    // 157
#define NSCHUNK ((NNODES + 255) / 256)              // 79 scan chunks per graph
#define STAGECAP 7424                               // >= SBSPAN + PCAP

typedef _Float16 half_t;
typedef __attribute__((ext_vector_type(8))) _Float16 half8;
typedef __attribute__((ext_vector_type(4))) float floatx4;

// ---------------- conversions ----------------
__global__ void cvt_split_kernel(const float* __restrict__ in,
                                 half_t* __restrict__ hi, half_t* __restrict__ lo, long n4) {
    long i = (long)blockIdx.x * 256 + threadIdx.x;
    if (i >= n4) return;
    float4 v = *(const float4*)&in[i * 4];
    half_t h[4], l[4];
    h[0] = (half_t)v.x; l[0] = (half_t)(v.x - (float)h[0]);
    h[1] = (half_t)v.y; l[1] = (half_t)(v.y - (float)h[1]);
    h[2] = (half_t)v.z; l[2] = (half_t)(v.z - (float)h[2]);
    h[3] = (half_t)v.w; l[3] = (half_t)(v.w - (float)h[3]);
    *(unsigned long long*)&hi[i * 4] = *(unsigned long long*)h;
    *(unsigned long long*)&lo[i * 4] = *(unsigned long long*)l;
}

// ---------------- CSR build ----------------
__global__ __launch_bounds__(256) void part64_kernel(const int* __restrict__ edges,
                                                     int* __restrict__ bcnt,
                                                     int* __restrict__ pairs) {
    int g = blockIdx.y;
    int c = blockIdx.x;
    __shared__ int hist[NSB], gbase[NSB], cur[NSB];
    if (threadIdx.x < NSB) hist[threadIdx.x] = 0;
    __syncthreads();
    const int* srcp = edges + (long)g * 2 * NEDGES;
    const int* dstp = srcp + NEDGES;
    int e0 = c * ECHUNK + threadIdx.x;
    int s[8], d[8], sb[8];
#pragma unroll
    for (int i = 0; i < 8; i++) {
        int e = e0 + i * 256;
        if (e < NEDGES) {
            s[i] = srcp[e];
            d[i] = dstp[e];
            sb[i] = (int)((unsigned)d[i] / (unsigned)SBSPAN);
            atomicAdd(&hist[sb[i]], 1);
        } else sb[i] = -1;
    }
    __syncthreads();
    if (threadIdx.x < NSB) {
        int h = hist[threadIdx.x];
        gbase[threadIdx.x] = h ? atomicAdd(&bcnt[g * NSB + threadIdx.x], h) : 0;
        cur[threadIdx.x] = 0;
    }
    __syncthreads();
#pragma unroll
    for (int i = 0; i < 8; i++) {
        if (sb[i] >= 0) {
            int pos = gbase[sb[i]] + atomicAdd(&cur[sb[i]], 1);
            int v = s[i] | ((d[i] - sb[i] * SBSPAN) << 15);
            pairs[((long)(g * NSB + sb[i])) * PCAP + pos] = v;
        }
    }
}

__global__ __launch_bounds__(256) void count_sb_kernel(const int* __restrict__ pairs,
                                                       const int* __restrict__ bcnt,
                                                       int* __restrict__ counts) {
    int g = blockIdx.x >> 6, sb = blockIdx.x & 63;
    __shared__ int hist[SBSPAN];
    for (int i = threadIdx.x; i < SBSPAN; i += 256) hist[i] = 0;
    __syncthreads();
    int n0 = sb * SBSPAN;
    int cnt = bcnt[g * NSB + sb];
    const int* p = pairs + (long)(g * NSB + sb) * PCAP;
    for (int k = threadIdx.x; k < cnt; k += 256)
        atomicAdd(&hist[p[k] >> 15], 1);
    __syncthreads();
    int nn = min(SBSPAN, NNODES - n0);
    for (int i = threadIdx.x; i < nn; i += 256)
        counts[g * NNODES + n0 + i] = hist[i];
}

__global__ void scanA_kernel(const int* __restrict__ counts, int* __restrict__ bsum) {
    int g = blockIdx.x / NSCHUNK, ch = blockIdx.x % NSCHUNK;
    int i = ch * 256 + threadIdx.x;
    int v = (i < NNODES) ? counts[g * NNODES + i] + 1 : 0;
    for (int off = 32; off; off >>= 1) v += __shfl_down(v, off);
    __shared__ int ws[4];
    if ((threadIdx.x & 63) == 0) ws[threadIdx.x >> 6] = v;
    __syncthreads();
    if (threadIdx.x == 0) bsum[blockIdx.x] = ws[0] + ws[1] + ws[2] + ws[3];
}

__global__ void scanB_kernel(const int* __restrict__ bsum, int* __restrict__ boff,
                             int* __restrict__ rowptr) {
    int g = blockIdx.x;
    int tid = threadIdx.x;  // 128
    int v = (tid < NSCHUNK) ? bsum[g * NSCHUNK + tid] : 0;
    __shared__ int buf[128];
    buf[tid] = v;
    __syncthreads();
    for (int off = 1; off < 128; off <<= 1) {
        int t = (tid >= off) ? buf[tid - off] : 0;
        __syncthreads();
        buf[tid] += t;
        __syncthreads();
    }
    if (tid < NSCHUNK) boff[g * NSCHUNK + tid] = buf[tid] - v;
    if (tid == 127) rowptr[g * (NNODES + 1) + NNODES] = buf[127];   // == ETOT
}

__global__ void scanC_kernel(const int* __restrict__ counts, const int* __restrict__ boff,
                             int* __restrict__ rowptr) {
    int g = blockIdx.x / NSCHUNK, ch = blockIdx.x % NSCHUNK;
    int tid = threadIdx.x;
    int i = ch * 256 + tid;
    int v = (i < NNODES) ? counts[g * NNODES + i] + 1 : 0;
    __shared__ int buf[256];
    buf[tid] = v;
    __syncthreads();
    for (int off = 1; off < 256; off <<= 1) {
        int t = (tid >= off) ? buf[tid - off] : 0;
        __syncthreads();
        buf[tid] += t;
        __syncthreads();
    }
    int excl = boff[blockIdx.x] + buf[tid] - v;
    if (i < NNODES) rowptr[g * (NNODES + 1) + i] = excl;
}

__global__ __launch_bounds__(256) void fill_sb_kernel(const int* __restrict__ pairs,
                                                      const int* __restrict__ bcnt,
                                                      const int* __restrict__ rowptr,
                                                      int* __restrict__ csr_src) {
    int g = blockIdx.x >> 6, sb = blockIdx.x & 63;
    __shared__ int cur[SBSPAN];
    __shared__ int stage[STAGECAP];
    int n0 = sb * SBSPAN;
    int nn = min(SBSPAN, NNODES - n0);
    const int* rp = rowptr + g * (NNODES + 1);
    int base = rp[n0];
    int span = rp[n0 + nn] - base;
    for (int i = threadIdx.x; i < nn; i += 256) {
        int rb = rp[n0 + i] - base;
        stage[rb] = n0 + i;          // self loop occupies first slot
        cur[i] = rb + 1;
    }
    __syncthreads();
    int cnt = bcnt[g * NSB + sb];
    const int* p = pairs + (long)(g * NSB + sb) * PCAP;
    for (int k = threadIdx.x; k < cnt; k += 256) {
        int v = p[k];
        int pos = atomicAdd(&cur[v >> 15], 1);
        stage[pos] = v & 0x7fff;
    }
    __syncthreads();
    int* dst = csr_src + (long)g * ETOT + base;
    for (int k = threadIdx.x; k < span; k += 256) dst[k] = stage[k];
}

// ---------------- precompute was/wad ----------------
__global__ void prep_was_kernel(const float* __restrict__ W1, const float* __restrict__ W2,
                                const float* __restrict__ as1, const float* __restrict__ as2,
                                const float* __restrict__ ad1, const float* __restrict__ ad2,
                                float* __restrict__ was, float* __restrict__ wad) {
    int b = blockIdx.x;            // l*8 + z*4 + h
    int l = b >> 3, z = (b >> 2) & 1, h = b & 3;
    int k = threadIdx.x;           // 128
    const float* W  = z ? W2 : W1;
    const float* av = z ? as2 : as1;
    const float* dv = z ? ad2 : ad1;
    float s = 0.f, d = 0.f;
    for (int c = 0; c < 128; c++) {
        float w = W[(long)l * HC * EMB + (h * 128 + c) * 128 + k];
        s = fmaf(w, av[(l * 4 + h) * 128 + c], s);
        d = fmaf(w, dv[(l * 4 + h) * 128 + c], d);
    }
    long idx = ((l * 2 + z) * 4 + h) * 128 + k;
    was[idx] = s;
    wad[idx] = d;
}

// ---------------- pack score-weight matrices for MFMA (split fp16) ----------------
__global__ void pack_ws_kernel(const float* __restrict__ wasb, const float* __restrict__ wadb,
                               half_t* __restrict__ WS0h, half_t* __restrict__ WS0l,
                               half_t* __restrict__ WS1h, half_t* __restrict__ WS1l) {
    int b = blockIdx.x;   // 0..47
    int k = threadIdx.x;  // 128
    if (b < 16) {
        int z = b >> 3, d = (b >> 2) & 1, h = b & 3;
        const float* src = d ? wadb : wasb;
        float v = src[((long)z * 4 + h) * 128 + k];       // layer0 inst = z
        half_t hi = (half_t)v;
        WS0h[b * 128 + k] = hi;
        WS0l[b * 128 + k] = (half_t)(v - (float)hi);
    } else {
        int b2 = b - 16;
        int z = b2 >> 4, r = b2 & 15;
        float v = 0.f;
        if (r < 8) {
            int d = r >> 2, h = r & 3;
            const float* src = d ? wadb : wasb;
            v = src[((long)(2 + z) * 4 + h) * 128 + k];   // layer1 inst = 2+z
        }
        half_t hi = (half_t)v;
        WS1h[(z * 16 + r) * 128 + k] = hi;
        WS1l[(z * 16 + r) * 128 + k] = (half_t)(v - (float)hi);
    }
}

// ---------------- precompute fused projection M[inst][k][h*128+c] ----------------
__global__ void prep_M_kernel(const float* __restrict__ gW1, const float* __restrict__ gW2,
                              const float* __restrict__ lW1, const float* __restrict__ lW2,
                              half_t* __restrict__ Mh, half_t* __restrict__ Ml) {
    int k = blockIdx.x;            // 0..127 (output channel)
    int inst = blockIdx.y;         // l*2 + z
    int l = inst >> 1, z = inst & 1;
    int c = threadIdx.x;           // 0..127
    const float* gW = (z ? gW2 : gW1) + (long)l * HC * EMB;   // [512][128]
    const float* lW = (z ? lW2 : lW1) + (long)l * EMB * HC;   // [128][512]
    float acc[4] = {0.f, 0.f, 0.f, 0.f};
    for (int cp = 0; cp < 128; cp++) {
#pragma unroll
        for (int h = 0; h < 4; h++) {
            float lw = lW[(long)k * 512 + h * 128 + cp];
            float gw = gW[(long)(h * 128 + cp) * 128 + c];
            acc[h] = fmaf(lw, gw, acc[h]);
        }
    }
#pragma unroll
    for (int h = 0; h < 4; h++) {
        long o = ((long)inst * 128 + k) * 512 + h * 128 + c;
        half_t hi = (half_t)acc[h];
        Mh[o] = hi;
        Ml[o] = (half_t)(acc[h] - (float)hi);
    }
}

// cb[inst][k] = sum_j lW[k,j]*gb[j] + lb[k]
__global__ void prep_cb_kernel(const float* __restrict__ lW1, const float* __restrict__ lW2,
                               const float* __restrict__ gb1_, const float* __restrict__ gb2_,
                               const float* __restrict__ lb1_, const float* __restrict__ lb2_,
                               float* __restrict__ cb) {
    int inst = blockIdx.x;
    int l = inst >> 1, z = inst & 1;
    int k = threadIdx.x;
    const float* lW = (z ? lW2 : lW1) + (long)l * EMB * HC;
    const float* gb = (z ? gb2_ : gb1_) + l * HC;
    const float* lb = (z ? lb2_ : lb1_) + l * EMB;
    float a = lb[k];
    for (int j = 0; j < 512; j++) a = fmaf(lW[(long)k * 512 + j], gb[j], a);
    cb[inst * 128 + k] = a;
}

// ---------------- scores via MFMA (instance-strided batch over blockIdx.y) ----------------
__global__ __launch_bounds__(256) void scores_b(
    const half_t* __restrict__ Ahb, const half_t* __restrict__ Alb, long aInst,
    const half_t* __restrict__ WShb, const half_t* __restrict__ WSlb, long wInst, int wMask,
    float* __restrict__ outb, long oInst, int M, int OS, int CMAX) {
    int iy = blockIdx.y;
    const half_t* Ah = Ahb + (long)iy * aInst;
    const half_t* Al = Alb + (long)iy * aInst;
    const half_t* WSh = WShb + (long)(iy & wMask) * wInst;
    const half_t* WSl = WSlb + (long)(iy & wMask) * wInst;
    float* out = outb + (long)iy * oInst;
    __shared__ half_t Bh[16 * 128];
    __shared__ half_t Bl[16 * 128];
    int tid = threadIdx.x;
    *(half8*)&Bh[tid * 8] = *(const half8*)&WSh[tid * 8];
    *(half8*)&Bl[tid * 8] = *(const half8*)&WSl[tid * 8];
    __syncthreads();
    int wave = tid >> 6, lane = tid & 63;
    int l16 = lane & 15, chunk = lane >> 4;
    int r0 = blockIdx.x * 64 + wave * 16;
    int rowc = r0 + l16; if (rowc > M - 1) rowc = M - 1;
    floatx4 acc = (floatx4)0.f;
#pragma unroll
    for (int ko = 0; ko < 128; ko += 32) {
        half8 ah = *(const half8*)&Ah[(long)rowc * 128 + ko + chunk * 8];
        half8 al = *(const half8*)&Al[(long)rowc * 128 + ko + chunk * 8];
        half8 bh = *(const half8*)&Bh[l16 * 128 + ko + chunk * 8];
        half8 bl = *(const half8*)&Bl[l16 * 128 + ko + chunk * 8];
        acc = __builtin_amdgcn_mfma_f32_16x16x32_f16(ah, bh, acc, 0, 0, 0);
        acc = __builtin_amdgcn_mfma_f32_16x16x32_f16(ah, bl, acc, 0, 0, 0);
        acc = __builtin_amdgcn_mfma_f32_16x16x32_f16(al, bh, acc, 0, 0, 0);
    }
#pragma unroll
    for (int reg = 0; reg < 4; reg++) {
        int rr = r0 + chunk * 4 + reg;
        if (rr < M && l16 < CMAX) out[(long)rr * OS + l16] = acc[reg];
    }
}

// ---------------- fused aggregation + projection ----------------
// Block = 1024 threads (16 waves), NB=16 nodes, BOTH z. Y never touches HBM.
// Phase 1: wave w aggregates node n0+w for both z (identical math/order to the
//   unfused agg2), writes h/l-split Y rows into LDS with XOR-swizzled 16B granules
//   (G' = G ^ (node&7)) so phase-2 column reads are ~bank-conflict-free.
// Phase 2: wave w computes one 16x16 tile of X = relu(Y @ M^T + cb):
//   z = w>>3, col-tile j = w&7. A-fragments from LDS; B (M) fragments straight
//   from global (L2-resident, 512 KB/layer). Same 3-MFMA split + k-order as the
//   old gemm_b -> bitwise-identical output.
// SX=true (layer 0): shared X across z. SX=false (layer 1): per-z X0/X1.
template <bool SX>
__global__ __launch_bounds__(1024, 8) void aggproj_kernel(
    const half_t* __restrict__ X0b, const half_t* __restrict__ X1b, long xsT,
    const float* __restrict__ sAb, const float* __restrict__ sBb, int stsh, long ssT,
    const int* __restrict__ rowptr, const int* __restrict__ csr_src,
    const half_t* __restrict__ Mh_l, const half_t* __restrict__ Ml_l,
    const float* __restrict__ cb_l,
    half_t* __restrict__ Xouth, half_t* __restrict__ Xoutl, int t0) {
    __shared__ half_t Yh_lds[2 * 16 * 512];   // 32 KB
    __shared__ half_t Yl_lds[2 * 16 * 512];   // 32 KB

    int tz = blockIdx.y, t = t0 + tz;
    int n0 = blockIdx.x * 16;
    int w = threadIdx.x >> 6;        // wave 0..15 = node_local
    int lane = threadIdx.x & 63;
    int h = lane >> 4, cg = lane & 15;

    // ---- phase 1: aggregate node n0+w, both z ----
    {
        int n = n0 + w;
        const int* rp = rowptr + t * (NNODES + 1);
        int beg = rp[n], end = rp[n + 1];
        const int* cs = csr_src + (long)t * ETOT;
        const half_t* X0 = X0b + (long)tz * xsT;
        const half_t* X1 = SX ? X0 : (X1b + (long)tz * xsT);
        const float* sA = sAb + (long)tz * ssT;
        const float* sB = sBb + (long)tz * ssT;
        float sd0 = sA[((long)n << stsh) + 4 + h];
        float sd1 = sB[((long)n << stsh) + 4 + h];
        float acc0[8], acc1[8];
#pragma unroll
        for (int c = 0; c < 8; c++) { acc0[c] = 0.f; acc1[c] = 0.f; }
        float den0 = 0.f, den1 = 0.f;

        auto proc2 = [&](int s0, int s1) {
            float va0 = sA[((long)s0 << stsh) + h];
            float vb0 = sB[((long)s0 << stsh) + h];
            float va1 = sA[((long)s1 << stsh) + h];
            float vb1 = sB[((long)s1 << stsh) + h];
            half8 xa0 = *(const half8*)&X0[(long)s0 * 128 + cg * 8];
            half8 xa1 = *(const half8*)&X0[(long)s1 * 128 + cg * 8];
            half8 xb0, xb1;
            if (!SX) {
                xb0 = *(const half8*)&X1[(long)s0 * 128 + cg * 8];
                xb1 = *(const half8*)&X1[(long)s1 * 128 + cg * 8];
            }
            float La0 = va0 + sd0, Lb0 = vb0 + sd1;
            float La1 = va1 + sd0, Lb1 = vb1 + sd1;
            float wa0 = __expf(fmaxf(La0, NEG_SLOPE * La0));
            float wb0 = __expf(fmaxf(Lb0, NEG_SLOPE * Lb0));
            float wa1 = __expf(fmaxf(La1, NEG_SLOPE * La1));
            float wb1 = __expf(fmaxf(Lb1, NEG_SLOPE * Lb1));
            den0 += wa0 + wa1;
            den1 += wb0 + wb1;
#pragma unroll
            for (int c = 0; c < 8; c++) {
                float a = acc0[c];
                a = fmaf(wa0, (float)xa0[c], a);
                a = fmaf(wa1, (float)xa1[c], a);
                acc0[c] = a;
                float b = acc1[c];
                b = fmaf(wb0, (float)(SX ? xa0[c] : xb0[c]), b);
                b = fmaf(wb1, (float)(SX ? xa1[c] : xb1[c]), b);
                acc1[c] = b;
            }
        };

        int j = beg;
        if (end - beg >= 4) {
            int a0 = cs[j], a1 = cs[j + 1];
            while (j + 4 <= end) {
                int b0 = cs[j + 2], b1 = cs[j + 3];
                proc2(a0, a1);
                a0 = b0; a1 = b1;
                j += 2;
            }
            proc2(a0, a1);
            j += 2;
        }
        for (; j < end; j++) {
            int src = cs[j];
            float va = sA[((long)src << stsh) + h];
            float vb = sB[((long)src << stsh) + h];
            half8 xa = *(const half8*)&X0[(long)src * 128 + cg * 8];
            half8 xb;
            if (!SX) xb = *(const half8*)&X1[(long)src * 128 + cg * 8];
            float La = va + sd0, Lb = vb + sd1;
            float wa = __expf(fmaxf(La, NEG_SLOPE * La));
            float wb = __expf(fmaxf(Lb, NEG_SLOPE * Lb));
            den0 += wa;
            den1 += wb;
#pragma unroll
            for (int c = 0; c < 8; c++) {
                acc0[c] = fmaf(wa, (float)xa[c], acc0[c]);
                acc1[c] = fmaf(wb, (float)(SX ? xa[c] : xb[c]), acc1[c]);
            }
        }

        float inv0 = 1.0f / den0;
        float inv1 = 1.0f / den1;
        half8 oh0, ol0, oh1, ol1;
#pragma unroll
        for (int c = 0; c < 8; c++) {
            float v0 = acc0[c] * inv0;
            half_t h0 = (half_t)v0;
            oh0[c] = h0; ol0[c] = (half_t)(v0 - (float)h0);
            float v1 = acc1[c] * inv1;
            half_t h1 = (half_t)v1;
            oh1[c] = h1; ol1[c] = (half_t)(v1 - (float)h1);
        }
        int Gp = (h * 16 + cg) ^ (w & 7);          // swizzled 16B-granule index
        *(half8*)&Yh_lds[((0 * 16 + w) * 64 + Gp) * 8] = oh0;
        *(half8*)&Yl_lds[((0 * 16 + w) * 64 + Gp) * 8] = ol0;
        *(half8*)&Yh_lds[((1 * 16 + w) * 64 + Gp) * 8] = oh1;
        *(half8*)&Yl_lds[((1 * 16 + w) * 64 + Gp) * 8] = ol1;
    }
    __syncthreads();

    // ---- phase 2: X[z][16 nodes][128] = relu(Y @ M^T + cb), one tile per wave ----
    {
        int z2 = w >> 3, jt = w & 7;
        const half_t* __restrict__ Bh = Mh_l + (long)z2 * EMB * HC;
        const half_t* __restrict__ Bl = Ml_l + (long)z2 * EMB * HC;
        const float* __restrict__ bias = cb_l + z2 * EMB;
        int l16 = lane & 15, chunk = lane >> 4;
        floatx4 acc = (floatx4)0.f;
#pragma unroll
        for (int kc = 0; kc < 16; kc++) {
            int Gp = (kc * 4 + chunk) ^ (l16 & 7);
            half8 ah = *(const half8*)&Yh_lds[((z2 * 16 + l16) * 64 + Gp) * 8];
            half8 al = *(const half8*)&Yl_lds[((z2 * 16 + l16) * 64 + Gp) * 8];
            long bo = (long)(jt * 16 + l16) * HC + kc * 32 + chunk * 8;
            half8 bh = *(const half8*)&Bh[bo];
            half8 bl = *(const half8*)&Bl[bo];
            acc = __builtin_amdgcn_mfma_f32_16x16x32_f16(ah, bh, acc, 0, 0, 0);
            acc = __builtin_amdgcn_mfma_f32_16x16x32_f16(ah, bl, acc, 0, 0, 0);
            acc = __builtin_amdgcn_mfma_f32_16x16x32_f16(al, bh, acc, 0, 0, 0);
        }
        // C/D layout: col = lane&15, row = (lane>>4)*4 + reg
        int r4 = (lane >> 4) * 4;
        long gz = (long)tz * 2 + z2;
        int col = jt * 16 + l16;
        float bv = bias[col];
#pragma unroll
        for (int reg = 0; reg < 4; reg++) {
            int row = r4 + reg;                   // node_local
            float v = fmaxf(acc[reg] + bv, 0.f);
            long o = (gz * NNODES + n0 + row) * EMB + col;
            half_t hi = (half_t)v;
            Xouth[o] = hi;
            Xoutl[o] = (half_t)(v - (float)hi);
        }
    }
}

// ---------------- fc1 split-K partial: grid (M/128, KS). K-slice per block. ------------
__global__ __launch_bounds__(256) void fc1_part_kernel(
    const half_t* __restrict__ Ah, const half_t* __restrict__ Al,
    const half_t* __restrict__ Bh, const half_t* __restrict__ Bl,
    float* __restrict__ pbuf, int M, int N, int K, int kslice) {
    const int ks = blockIdx.y;
    const int kbeg = ks * kslice;
    const int kend = kbeg + kslice;

    __shared__ half_t Ash[4 * 128 * 8];
    __shared__ half_t Asl[4 * 128 * 8];
    __shared__ half_t Bsh[4 * 128 * 8];
    __shared__ half_t Bsl[4 * 128 * 8];

    const int tid = threadIdx.x;
    const int row0 = blockIdx.x * 128;
    const int wave = tid >> 6;
    const int lane = tid & 63;
    const int wm = (wave >> 1) * 64;
    const int wn = (wave & 1) * 64;
    const int chunk = lane >> 4;
    const int l16 = lane & 15;

    floatx4 acc[4][4];
#pragma unroll
    for (int ii = 0; ii < 4; ii++)
#pragma unroll
        for (int j = 0; j < 4; j++) acc[ii][j] = (floatx4)0.0f;

    for (int k0 = kbeg; k0 < kend; k0 += 32) {
        __syncthreads();
#pragma unroll
        for (int p = 0; p < 2; p++) {
            int idx = p * 256 + tid;
            int r = idx >> 2, kc = idx & 3;
            long aoff = (long)(row0 + r) * K + k0 + kc * 8;
            *(half8*)&Ash[(kc * 128 + r) * 8] = *(const half8*)&Ah[aoff];
            *(half8*)&Asl[(kc * 128 + r) * 8] = *(const half8*)&Al[aoff];
            long boff = (long)r * K + k0 + kc * 8;
            *(half8*)&Bsh[(kc * 128 + r) * 8] = *(const half8*)&Bh[boff];
            *(half8*)&Bsl[(kc * 128 + r) * 8] = *(const half8*)&Bl[boff];
        }
        __syncthreads();
        half8 afh[4], afl[4], bfh[4], bfl[4];
#pragma unroll
        for (int mi = 0; mi < 4; mi++) {
            int o = (chunk * 128 + wm + mi * 16 + l16) * 8;
            afh[mi] = *(const half8*)&Ash[o];
            afl[mi] = *(const half8*)&Asl[o];
        }
#pragma unroll
        for (int ni = 0; ni < 4; ni++) {
            int o = (chunk * 128 + wn + ni * 16 + l16) * 8;
            bfh[ni] = *(const half8*)&Bsh[o];
            bfl[ni] = *(const half8*)&Bsl[o];
        }
#pragma unroll
        for (int mi = 0; mi < 4; mi++)
#pragma unroll
            for (int ni = 0; ni < 4; ni++) {
                acc[mi][ni] = __builtin_amdgcn_mfma_f32_16x16x32_f16(
                    afh[mi], bfh[ni], acc[mi][ni], 0, 0, 0);
                acc[mi][ni] = __builtin_amdgcn_mfma_f32_16x16x32_f16(
                    afh[mi], bfl[ni], acc[mi][ni], 0, 0, 0);
                acc[mi][ni] = __builtin_amdgcn_mfma_f32_16x16x32_f16(
                    afl[mi], bfh[ni], acc[mi][ni], 0, 0, 0);
            }
    }

    const int r4 = (lane >> 4) * 4;
#pragma unroll
    for (int mi = 0; mi < 4; mi++)
#pragma unroll
        for (int reg = 0; reg < 4; reg++) {
            int row = row0 + wm + mi * 16 + r4 + reg;
#pragma unroll
            for (int ni = 0; ni < 4; ni++) {
                int col = wn + ni * 16 + l16;
                pbuf[((long)ks * M + row) * N + col] = acc[mi][ni][reg];
            }
        }
}

// fc1 reduce: h1[i] = relu(sum_ks pbuf[ks][i] + bias[i % N])
__global__ void fc1_reduce_kernel(const float* __restrict__ pbuf, const float* __restrict__ bias,
                                  float* __restrict__ h1, int MN, int KS) {
    int i = blockIdx.x * 256 + threadIdx.x;
    if (i >= MN) return;
    float a = 0.f;
    for (int ks = 0; ks < KS; ks++) a += pbuf[(long)ks * MN + i];
    h1[i] = fmaxf(a + bias[i & (EMB - 1)], 0.f);
}

// ---------------- gather clf_nodes into flat MLP input (reversed timesteps, batched) ------
__global__ void gather_kernel(const half_t* __restrict__ Xh, const half_t* __restrict__ Xl,
                              const int* __restrict__ clf,
                              half_t* __restrict__ flath, half_t* __restrict__ flatl, int t0) {
    int b = blockIdx.x;
    int z = blockIdx.y;
    int tz = blockIdx.z;
    int t = t0 + tz, gz = tz * 2 + z;
    int j = threadIdx.x;  // 64 dwords = 128 halves
    int node = clf[b];
    long dst = (long)b * (TSTEPS * 2 * EMB) + (TSTEPS - 1 - t) * (2 * EMB) + z * EMB;
    long src = ((long)gz * NNODES + node) * EMB;
    ((unsigned int*)&flath[dst])[j] = ((const unsigned int*)&Xh[src])[j];
    ((unsigned int*)&flatl[dst])[j] = ((const unsigned int*)&Xl[src])[j];
}

// ---------------- fc2: [B,128] @ [2,128]^T + bias, relu, fp32 out ----------------
__global__ void fc2_kernel(const float* __restrict__ h1, const float* __restrict__ W,
                           const float* __restrict__ bias, float* __restrict__ out) {
    int row = blockIdx.x;
    int lane = threadIdx.x;  // 64
    float x0 = h1[(long)row * 128 + lane];
    float x1 = h1[(long)row * 128 + 64 + lane];
    float p0 = x0 * W[lane] + x1 * W[64 + lane];
    float p1 = x0 * W[128 + lane] + x1 * W[192 + lane];
    for (int off = 32; off; off >>= 1) {
        p0 += __shfl_down(p0, off);
        p1 += __shfl_down(p1, off);
    }
    if (lane == 0) {
        out[row * 2 + 0] = fmaxf(p0 + bias[0], 0.f);
        out[row * 2 + 1] = fmaxf(p1 + bias[1], 0.f);
    }
}

extern "C" void kernel_launch(void* const* d_in, const int* in_sizes, int n_in,
                              void* d_out, int out_size, void* d_ws, size_t ws_size,
                              hipStream_t stream) {
    const float* emb     = (const float*)d_in[0];
    const int*   edges   = (const int*)d_in[1];
    const int*   clf     = (const int*)d_in[5];
    const float* gat_W1  = (const float*)d_in[6];
    const float* gat_as1 = (const float*)d_in[7];
    const float* gat_ad1 = (const float*)d_in[8];
    const float* gat_b1  = (const float*)d_in[9];
    const float* lin_W1  = (const float*)d_in[10];
    const float* lin_b1  = (const float*)d_in[11];
    const float* gat_W2  = (const float*)d_in[12];
    const float* gat_as2 = (const float*)d_in[13];
    const float* gat_ad2 = (const float*)d_in[14];
    const float* gat_b2  = (const float*)d_in[15];
    const float* lin_W2  = (const float*)d_in[16];
    const float* lin_b2  = (const float*)d_in[17];
    const float* fc1_W   = (const float*)d_in[18];
    const float* fc1_b   = (const float*)d_in[19];
    const float* fc2_W   = (const float*)d_in[20];
    const float* fc2_b   = (const float*)d_in[21];
    float* out = (float*)d_out;

    char* ws = (char*)d_ws;
    size_t off = 0;
    auto alloc = [&](size_t bytes) -> char* {
        char* p = ws + off;
        off += (bytes + 255) & ~(size_t)255;
        return p;
    };
    // ---- fixed, both-phase allocations ----
    int* counts  = (int*)alloc((size_t)TSTEPS * NNODES * 4);
    int* rowptr  = (int*)alloc((size_t)TSTEPS * (NNODES + 1) * 4);
    int* csr_src = (int*)alloc((size_t)TSTEPS * ETOT * 4);
    int* bsum    = (int*)alloc((size_t)TSTEPS * NSCHUNK * 4);
    int* boff    = (int*)alloc((size_t)TSTEPS * NSCHUNK * 4);
    int* bcnt    = (int*)alloc((size_t)TSTEPS * NSB * 4);
    half_t* embh = (half_t*)alloc((size_t)TSTEPS * NNODES * EMB * 2);
    half_t* Mh   = (half_t*)alloc((size_t)4 * EMB * HC * 2);
    half_t* Ml   = (half_t*)alloc((size_t)4 * EMB * HC * 2);
    float*  cb   = (float*)alloc((size_t)4 * EMB * 4);
    half_t* fc1Wh = (half_t*)alloc((size_t)EMB * 2 * EMB * TSTEPS * 2);
    half_t* fc1Wl = (half_t*)alloc((size_t)EMB * 2 * EMB * TSTEPS * 2);
    float* wasb = (float*)alloc((size_t)2 * 2 * 4 * 128 * 4);
    float* wadb = (float*)alloc((size_t)2 * 2 * 4 * 128 * 4);
    half_t* WS0h = (half_t*)alloc((size_t)16 * 128 * 2);
    half_t* WS0l = (half_t*)alloc((size_t)16 * 128 * 2);
    half_t* WS1h = (half_t*)alloc((size_t)2 * 16 * 128 * 2);
    half_t* WS1l = (half_t*)alloc((size_t)2 * 16 * 128 * 2);
    float* s0buf = (float*)alloc((size_t)TSTEPS * NNODES * 16 * 4);   // [t][n][16]
    half_t* flath = (half_t*)alloc((size_t)BCLF * (TSTEPS * 2 * EMB) * 2);
    half_t* flatl = (half_t*)alloc((size_t)BCLF * (TSTEPS * 2 * EMB) * 2);
    float* h1buf = (float*)alloc((size_t)BCLF * EMB * 4);

    // ---- phase-overlapped region: {embl, pairs} (pre-loop) aliases loop buffers ----
    size_t region_base = off;
    half_t* embl = (half_t*)alloc((size_t)TSTEPS * NNODES * EMB * 2);
    int* pairs   = (int*)alloc((size_t)TSTEPS * NSB * PCAP * 4);

    // per-timestep loop footprint: Xh+Xl (layer-0 out) + X2h+X2l (layer-1 out) + s1
    const size_t perT = ((size_t)2 * NNODES * EMB * 2 * 2) * 2 +  // X + X2 (h,l each)
                        ((size_t)2 * NNODES * 8 * 4) + 4096;      // s1 + align slop
    int TG = 1;
    if (ws_size > region_base + perT) {
        size_t cap = (ws_size - region_base) / perT;
        TG = (cap >= 10) ? 10 : (int)cap;
        if (TG < 1) TG = 1;
    }
    off = region_base;  // loop-phase buffers alias embl/pairs
    half_t* Xh  = (half_t*)alloc((size_t)TG * 2 * NNODES * EMB * 2);
    half_t* Xl  = (half_t*)alloc((size_t)TG * 2 * NNODES * EMB * 2);
    half_t* X2h = (half_t*)alloc((size_t)TG * 2 * NNODES * EMB * 2);
    half_t* X2l = (half_t*)alloc((size_t)TG * 2 * NNODES * EMB * 2);
    float* s1buf = (float*)alloc((size_t)TG * 2 * NNODES * 8 * 4);

    // ---- conversions + fused-weight precompute ----
    {
        long n4 = (long)TSTEPS * NNODES * EMB / 4;
        cvt_split_kernel<<<(int)((n4 + 255) / 256), 256, 0, stream>>>(emb, embh, embl, n4);
        long f4 = (long)EMB * 2 * EMB * TSTEPS / 4;
        cvt_split_kernel<<<(int)((f4 + 255) / 256), 256, 0, stream>>>(fc1_W, fc1Wh, fc1Wl, f4);
    }
    prep_was_kernel<<<16, 128, 0, stream>>>(gat_W1, gat_W2, gat_as1, gat_as2,
                                            gat_ad1, gat_ad2, wasb, wadb);
    pack_ws_kernel<<<48, 128, 0, stream>>>(wasb, wadb, WS0h, WS0l, WS1h, WS1l);
    prep_M_kernel<<<dim3(128, 4), 128, 0, stream>>>(gat_W1, gat_W2, lin_W1, lin_W2, Mh, Ml);
    prep_cb_kernel<<<4, 128, 0, stream>>>(lin_W1, lin_W2, gat_b1, gat_b2, lin_b1, lin_b2, cb);

    // layer-0 scores for all timesteps, both z: [200000,128]@[128,16] (uses embl)
    scores_b<<<dim3(3125, 1), 256, 0, stream>>>(
        embh, embl, 0, WS0h, WS0l, 0, 0, s0buf, 0, TSTEPS * NNODES, 16, 16);

    // ---- CSR build: partition -> count -> scan -> staged fill ----
    hipMemsetAsync(bcnt, 0, (size_t)TSTEPS * NSB * 4, stream);
    part64_kernel<<<dim3(NCHUNKS, TSTEPS), 256, 0, stream>>>(edges, bcnt, pairs);
    count_sb_kernel<<<NSB * TSTEPS, 256, 0, stream>>>(pairs, bcnt, counts);
    scanA_kernel<<<TSTEPS * NSCHUNK, 256, 0, stream>>>(counts, bsum);
    scanB_kernel<<<TSTEPS, 128, 0, stream>>>(bsum, boff, rowptr);
    scanC_kernel<<<TSTEPS * NSCHUNK, 256, 0, stream>>>(counts, boff, rowptr);
    fill_sb_kernel<<<NSB * TSTEPS, 256, 0, stream>>>(pairs, bcnt, rowptr, csr_src);
    // (pairs/embl dead from here on; loop-phase buffers may overwrite them)

    for (int t0 = 0; t0 < TSTEPS; t0 += TG) {
        int tg = (TSTEPS - t0 < TG) ? (TSTEPS - t0) : TG;
        // ---- layer 0: fused agg+proj (shared X = embeddings) -> X ----
        aggproj_kernel<true><<<dim3(NNODES / 16, tg), 1024, 0, stream>>>(
            embh + (long)t0 * NNODES * EMB, nullptr, (long)NNODES * EMB,
            s0buf + (long)t0 * NNODES * 16, s0buf + (long)t0 * NNODES * 16 + 8,
            4, (long)NNODES * 16,
            rowptr, csr_src,
            Mh, Ml, cb,
            Xh, Xl, t0);
        // layer-1 scores from X
        scores_b<<<dim3(313, 2 * tg), 256, 0, stream>>>(
            Xh, Xl, (long)NNODES * EMB,
            WS1h, WS1l, (long)16 * 128, 1,
            s1buf, (long)NNODES * 8, NNODES, 8, 8);
        // ---- layer 1: fused agg+proj (per-z X) -> X2 ----
        aggproj_kernel<false><<<dim3(NNODES / 16, tg), 1024, 0, stream>>>(
            Xh, Xh + (long)NNODES * EMB, (long)2 * NNODES * EMB,
            s1buf, s1buf + (long)NNODES * 8, 3, (long)2 * NNODES * 8,
            rowptr, csr_src,
            Mh + (long)2 * EMB * HC, Ml + (long)2 * EMB * HC, cb + 2 * EMB,
            X2h, X2l, t0);
        gather_kernel<<<dim3(BCLF, 2, tg), 64, 0, stream>>>(X2h, X2l, clf, flath, flatl, t0);
    }
    // ---- head MLP: split-K fc1 (partials aliased onto dead loop region) + reduce + fc2 ----
    float* pbuf = (float*)(ws + region_base);   // 8*4096*128*4 = 16.8 MB << region
    fc1_part_kernel<<<dim3(32, 8), 256, 0, stream>>>(
        flath, flatl, fc1Wh, fc1Wl, pbuf, BCLF, EMB, TSTEPS * 2 * EMB, (TSTEPS * 2 * EMB) / 8);
    fc1_reduce_kernel<<<(BCLF * EMB + 255) / 256, 256, 0, stream>>>(
        pbuf, fc1_b, h1buf, BCLF * EMB, 8);
    fc2_kernel<<<BCLF, 64, 0, stream>>>(h1buf, fc2_W, fc2_b, out);
}

// Round 7
// 1711.796 us; speedup vs baseline: 1.4319x; 1.4319x over previous
//
#include <hip/hip_runtime.h>
#include <cstdint>

#define NNODES 20000
#define NEDGES 320000
#define ETOT   340000   // NEDGES + NNODES self loops
#define TSTEPS 10
#define BCLF   4096
#define EMB    128
#define HC     512      // HEADS * EMB
#define NEG_SLOPE 0.2f

// CSR build: 64 dst sub-buckets per graph, packed records, LDS-staged fill
#define NSB    64
#define SBSPAN 313                                  // ceil(20000/64); 64*313 = 20032
#define PCAP   6912                                 // mean 5008 + 27 sigma
#define ECHUNK 2048
#define NCHUNKS ((NEDGES + ECHUNK - 1) / ECHUNK)    // 157
#define NSCHUNK ((NNODES + 255) / 256)              // 79 scan chunks per graph
#define STAGECAP 7424                               // >= SBSPAN + PCAP

typedef _Float16 half_t;
typedef __attribute__((ext_vector_type(8))) _Float16 half8;
typedef __attribute__((ext_vector_type(4))) float floatx4;

// ---------------- conversions ----------------
__global__ void cvt_split_kernel(const float* __restrict__ in,
                                 half_t* __restrict__ hi, half_t* __restrict__ lo, long n4) {
    long i = (long)blockIdx.x * 256 + threadIdx.x;
    if (i >= n4) return;
    float4 v = *(const float4*)&in[i * 4];
    half_t h[4], l[4];
    h[0] = (half_t)v.x; l[0] = (half_t)(v.x - (float)h[0]);
    h[1] = (half_t)v.y; l[1] = (half_t)(v.y - (float)h[1]);
    h[2] = (half_t)v.z; l[2] = (half_t)(v.z - (float)h[2]);
    h[3] = (half_t)v.w; l[3] = (half_t)(v.w - (float)h[3]);
    *(unsigned long long*)&hi[i * 4] = *(unsigned long long*)h;
    *(unsigned long long*)&lo[i * 4] = *(unsigned long long*)l;
}

// ---------------- CSR build ----------------
__global__ __launch_bounds__(256) void part64_kernel(const int* __restrict__ edges,
                                                     int* __restrict__ bcnt,
                                                     int* __restrict__ pairs) {
    int g = blockIdx.y;
    int c = blockIdx.x;
    __shared__ int hist[NSB], gbase[NSB], cur[NSB];
    if (threadIdx.x < NSB) hist[threadIdx.x] = 0;
    __syncthreads();
    const int* srcp = edges + (long)g * 2 * NEDGES;
    const int* dstp = srcp + NEDGES;
    int e0 = c * ECHUNK + threadIdx.x;
    int s[8], d[8], sb[8];
#pragma unroll
    for (int i = 0; i < 8; i++) {
        int e = e0 + i * 256;
        if (e < NEDGES) {
            s[i] = srcp[e];
            d[i] = dstp[e];
            sb[i] = (int)((unsigned)d[i] / (unsigned)SBSPAN);
            atomicAdd(&hist[sb[i]], 1);
        } else sb[i] = -1;
    }
    __syncthreads();
    if (threadIdx.x < NSB) {
        int h = hist[threadIdx.x];
        gbase[threadIdx.x] = h ? atomicAdd(&bcnt[g * NSB + threadIdx.x], h) : 0;
        cur[threadIdx.x] = 0;
    }
    __syncthreads();
#pragma unroll
    for (int i = 0; i < 8; i++) {
        if (sb[i] >= 0) {
            int pos = gbase[sb[i]] + atomicAdd(&cur[sb[i]], 1);
            int v = s[i] | ((d[i] - sb[i] * SBSPAN) << 15);
            pairs[((long)(g * NSB + sb[i])) * PCAP + pos] = v;
        }
    }
}

__global__ __launch_bounds__(256) void count_sb_kernel(const int* __restrict__ pairs,
                                                       const int* __restrict__ bcnt,
                                                       int* __restrict__ counts) {
    int g = blockIdx.x >> 6, sb = blockIdx.x & 63;
    __shared__ int hist[SBSPAN];
    for (int i = threadIdx.x; i < SBSPAN; i += 256) hist[i] = 0;
    __syncthreads();
    int n0 = sb * SBSPAN;
    int cnt = bcnt[g * NSB + sb];
    const int* p = pairs + (long)(g * NSB + sb) * PCAP;
    for (int k = threadIdx.x; k < cnt; k += 256)
        atomicAdd(&hist[p[k] >> 15], 1);
    __syncthreads();
    int nn = min(SBSPAN, NNODES - n0);
    for (int i = threadIdx.x; i < nn; i += 256)
        counts[g * NNODES + n0 + i] = hist[i];
}

__global__ void scanA_kernel(const int* __restrict__ counts, int* __restrict__ bsum) {
    int g = blockIdx.x / NSCHUNK, ch = blockIdx.x % NSCHUNK;
    int i = ch * 256 + threadIdx.x;
    int v = (i < NNODES) ? counts[g * NNODES + i] + 1 : 0;
    for (int off = 32; off; off >>= 1) v += __shfl_down(v, off);
    __shared__ int ws[4];
    if ((threadIdx.x & 63) == 0) ws[threadIdx.x >> 6] = v;
    __syncthreads();
    if (threadIdx.x == 0) bsum[blockIdx.x] = ws[0] + ws[1] + ws[2] + ws[3];
}

__global__ void scanB_kernel(const int* __restrict__ bsum, int* __restrict__ boff,
                             int* __restrict__ rowptr) {
    int g = blockIdx.x;
    int tid = threadIdx.x;  // 128
    int v = (tid < NSCHUNK) ? bsum[g * NSCHUNK + tid] : 0;
    __shared__ int buf[128];
    buf[tid] = v;
    __syncthreads();
    for (int off = 1; off < 128; off <<= 1) {
        int t = (tid >= off) ? buf[tid - off] : 0;
        __syncthreads();
        buf[tid] += t;
        __syncthreads();
    }
    if (tid < NSCHUNK) boff[g * NSCHUNK + tid] = buf[tid] - v;
    if (tid == 127) rowptr[g * (NNODES + 1) + NNODES] = buf[127];   // == ETOT
}

__global__ void scanC_kernel(const int* __restrict__ counts, const int* __restrict__ boff,
                             int* __restrict__ rowptr) {
    int g = blockIdx.x / NSCHUNK, ch = blockIdx.x % NSCHUNK;
    int tid = threadIdx.x;
    int i = ch * 256 + tid;
    int v = (i < NNODES) ? counts[g * NNODES + i] + 1 : 0;
    __shared__ int buf[256];
    buf[tid] = v;
    __syncthreads();
    for (int off = 1; off < 256; off <<= 1) {
        int t = (tid >= off) ? buf[tid - off] : 0;
        __syncthreads();
        buf[tid] += t;
        __syncthreads();
    }
    int excl = boff[blockIdx.x] + buf[tid] - v;
    if (i < NNODES) rowptr[g * (NNODES + 1) + i] = excl;
}

__global__ __launch_bounds__(256) void fill_sb_kernel(const int* __restrict__ pairs,
                                                      const int* __restrict__ bcnt,
                                                      const int* __restrict__ rowptr,
                                                      int* __restrict__ csr_src) {
    int g = blockIdx.x >> 6, sb = blockIdx.x & 63;
    __shared__ int cur[SBSPAN];
    __shared__ int stage[STAGECAP];
    int n0 = sb * SBSPAN;
    int nn = min(SBSPAN, NNODES - n0);
    const int* rp = rowptr + g * (NNODES + 1);
    int base = rp[n0];
    int span = rp[n0 + nn] - base;
    for (int i = threadIdx.x; i < nn; i += 256) {
        int rb = rp[n0 + i] - base;
        stage[rb] = n0 + i;          // self loop occupies first slot
        cur[i] = rb + 1;
    }
    __syncthreads();
    int cnt = bcnt[g * NSB + sb];
    const int* p = pairs + (long)(g * NSB + sb) * PCAP;
    for (int k = threadIdx.x; k < cnt; k += 256) {
        int v = p[k];
        int pos = atomicAdd(&cur[v >> 15], 1);
        stage[pos] = v & 0x7fff;
    }
    __syncthreads();
    int* dst = csr_src + (long)g * ETOT + base;
    for (int k = threadIdx.x; k < span; k += 256) dst[k] = stage[k];
}

// ---------------- precompute was/wad ----------------
__global__ void prep_was_kernel(const float* __restrict__ W1, const float* __restrict__ W2,
                                const float* __restrict__ as1, const float* __restrict__ as2,
                                const float* __restrict__ ad1, const float* __restrict__ ad2,
                                float* __restrict__ was, float* __restrict__ wad) {
    int b = blockIdx.x;            // l*8 + z*4 + h
    int l = b >> 3, z = (b >> 2) & 1, h = b & 3;
    int k = threadIdx.x;           // 128
    const float* W  = z ? W2 : W1;
    const float* av = z ? as2 : as1;
    const float* dv = z ? ad2 : ad1;
    float s = 0.f, d = 0.f;
    for (int c = 0; c < 128; c++) {
        float w = W[(long)l * HC * EMB + (h * 128 + c) * 128 + k];
        s = fmaf(w, av[(l * 4 + h) * 128 + c], s);
        d = fmaf(w, dv[(l * 4 + h) * 128 + c], d);
    }
    long idx = ((l * 2 + z) * 4 + h) * 128 + k;
    was[idx] = s;
    wad[idx] = d;
}

// ---------------- pack score-weight matrices for MFMA (split fp16) ----------------
__global__ void pack_ws_kernel(const float* __restrict__ wasb, const float* __restrict__ wadb,
                               half_t* __restrict__ WS0h, half_t* __restrict__ WS0l,
                               half_t* __restrict__ WS1h, half_t* __restrict__ WS1l) {
    int b = blockIdx.x;   // 0..47
    int k = threadIdx.x;  // 128
    if (b < 16) {
        int z = b >> 3, d = (b >> 2) & 1, h = b & 3;
        const float* src = d ? wadb : wasb;
        float v = src[((long)z * 4 + h) * 128 + k];       // layer0 inst = z
        half_t hi = (half_t)v;
        WS0h[b * 128 + k] = hi;
        WS0l[b * 128 + k] = (half_t)(v - (float)hi);
    } else {
        int b2 = b - 16;
        int z = b2 >> 4, r = b2 & 15;
        float v = 0.f;
        if (r < 8) {
            int d = r >> 2, h = r & 3;
            const float* src = d ? wadb : wasb;
            v = src[((long)(2 + z) * 4 + h) * 128 + k];   // layer1 inst = 2+z
        }
        half_t hi = (half_t)v;
        WS1h[(z * 16 + r) * 128 + k] = hi;
        WS1l[(z * 16 + r) * 128 + k] = (half_t)(v - (float)hi);
    }
}

// ---------------- precompute fused projection M[inst][k][h*128+c] ----------------
__global__ void prep_M_kernel(const float* __restrict__ gW1, const float* __restrict__ gW2,
                              const float* __restrict__ lW1, const float* __restrict__ lW2,
                              half_t* __restrict__ Mh, half_t* __restrict__ Ml) {
    int k = blockIdx.x;            // 0..127 (output channel)
    int inst = blockIdx.y;         // l*2 + z
    int l = inst >> 1, z = inst & 1;
    int c = threadIdx.x;           // 0..127
    const float* gW = (z ? gW2 : gW1) + (long)l * HC * EMB;   // [512][128]
    const float* lW = (z ? lW2 : lW1) + (long)l * EMB * HC;   // [128][512]
    float acc[4] = {0.f, 0.f, 0.f, 0.f};
    for (int cp = 0; cp < 128; cp++) {
#pragma unroll
        for (int h = 0; h < 4; h++) {
            float lw = lW[(long)k * 512 + h * 128 + cp];
            float gw = gW[(long)(h * 128 + cp) * 128 + c];
            acc[h] = fmaf(lw, gw, acc[h]);
        }
    }
#pragma unroll
    for (int h = 0; h < 4; h++) {
        long o = ((long)inst * 128 + k) * 512 + h * 128 + c;
        half_t hi = (half_t)acc[h];
        Mh[o] = hi;
        Ml[o] = (half_t)(acc[h] - (float)hi);
    }
}

// cb[inst][k] = sum_j lW[k,j]*gb[j] + lb[k]
__global__ void prep_cb_kernel(const float* __restrict__ lW1, const float* __restrict__ lW2,
                               const float* __restrict__ gb1_, const float* __restrict__ gb2_,
                               const float* __restrict__ lb1_, const float* __restrict__ lb2_,
                               float* __restrict__ cb) {
    int inst = blockIdx.x;
    int l = inst >> 1, z = inst & 1;
    int k = threadIdx.x;
    const float* lW = (z ? lW2 : lW1) + (long)l * EMB * HC;
    const float* gb = (z ? gb2_ : gb1_) + l * HC;
    const float* lb = (z ? lb2_ : lb1_) + l * EMB;
    float a = lb[k];
    for (int j = 0; j < 512; j++) a = fmaf(lW[(long)k * 512 + j], gb[j], a);
    cb[inst * 128 + k] = a;
}

// ---------------- scores via MFMA ----------------
// out row base = outb + (iy>>1)*oPair + (iy&1)*oZ  (tz = iy>>1, z = iy&1).
// L1 uses oPair = NNODES*16, oZ = 8 -> both z's scores share each node's 64-B row.
__global__ __launch_bounds__(256) void scores_b(
    const half_t* __restrict__ Ahb, const half_t* __restrict__ Alb, long aInst,
    const half_t* __restrict__ WShb, const half_t* __restrict__ WSlb, long wInst, int wMask,
    float* __restrict__ outb, long oPair, int oZ, int M, int OS, int CMAX) {
    int iy = blockIdx.y;
    const half_t* Ah = Ahb + (long)iy * aInst;
    const half_t* Al = Alb + (long)iy * aInst;
    const half_t* WSh = WShb + (long)(iy & wMask) * wInst;
    const half_t* WSl = WSlb + (long)(iy & wMask) * wInst;
    float* out = outb + (long)(iy >> 1) * oPair + (long)(iy & 1) * oZ;
    __shared__ half_t Bh[16 * 128];
    __shared__ half_t Bl[16 * 128];
    int tid = threadIdx.x;
    *(half8*)&Bh[tid * 8] = *(const half8*)&WSh[tid * 8];
    *(half8*)&Bl[tid * 8] = *(const half8*)&WSl[tid * 8];
    __syncthreads();
    int wave = tid >> 6, lane = tid & 63;
    int l16 = lane & 15, chunk = lane >> 4;
    int r0 = blockIdx.x * 64 + wave * 16;
    int rowc = r0 + l16; if (rowc > M - 1) rowc = M - 1;
    floatx4 acc = (floatx4)0.f;
#pragma unroll
    for (int ko = 0; ko < 128; ko += 32) {
        half8 ah = *(const half8*)&Ah[(long)rowc * 128 + ko + chunk * 8];
        half8 al = *(const half8*)&Al[(long)rowc * 128 + ko + chunk * 8];
        half8 bh = *(const half8*)&Bh[l16 * 128 + ko + chunk * 8];
        half8 bl = *(const half8*)&Bl[l16 * 128 + ko + chunk * 8];
        acc = __builtin_amdgcn_mfma_f32_16x16x32_f16(ah, bh, acc, 0, 0, 0);
        acc = __builtin_amdgcn_mfma_f32_16x16x32_f16(ah, bl, acc, 0, 0, 0);
        acc = __builtin_amdgcn_mfma_f32_16x16x32_f16(al, bh, acc, 0, 0, 0);
    }
#pragma unroll
    for (int reg = 0; reg < 4; reg++) {
        int rr = r0 + chunk * 4 + reg;
        if (rr < M && l16 < CMAX) out[(long)rr * OS + l16] = acc[reg];
    }
}

// ---------------- z-fused aggregation, PW-wide pipeline ----------------
// One wave per (tz, dst). lane: h = lane>>4, cg = lane&15 (8 ch each).
// SX=true (layer 0): X shared across z. SX=false (layer 1): per-z X0/X1.
// Score rows are [n][16] with z0 cols 0-7, z1 cols 8-15 (sB = sA + 8) -> both z's
// loads for an edge hit the same 64-B line. PW edges in flight with next-batch
// index prefetch. Per-node accumulation order stable across PW.
template <bool SX, int PW>
__global__ __launch_bounds__(256) void agg2_kernel(
    const half_t* __restrict__ X0b, const half_t* __restrict__ X1b, long xsT,
    const float* __restrict__ sAb, const float* __restrict__ sBb, int stsh, long ssT,
    const int* __restrict__ rowptr, const int* __restrict__ csr_src,
    half_t* __restrict__ Yh, half_t* __restrict__ Yl, int t0) {
    int tz = blockIdx.y, t = t0 + tz;
    int n = blockIdx.x * 4 + (threadIdx.x >> 6);
    int lane = threadIdx.x & 63;
    int h = lane >> 4, cg = lane & 15;
    const int* rp = rowptr + t * (NNODES + 1);
    int beg = rp[n], end = rp[n + 1];
    const int* cs = csr_src + (long)t * ETOT;
    const half_t* X0 = X0b + (long)tz * xsT;
    const half_t* X1 = SX ? X0 : (X1b + (long)tz * xsT);
    const float* sA = sAb + (long)tz * ssT;
    const float* sB = sBb + (long)tz * ssT;
    float sd0 = sA[((long)n << stsh) + 4 + h];
    float sd1 = sB[((long)n << stsh) + 4 + h];
    float acc0[8], acc1[8];
#pragma unroll
    for (int c = 0; c < 8; c++) { acc0[c] = 0.f; acc1[c] = 0.f; }
    float den0 = 0.f, den1 = 0.f;

    auto PROC = [&](const int* sv) {
        float va[PW], vb[PW];
        half8 xa[PW], xb[PW];
#pragma unroll
        for (int p = 0; p < PW; p++) {
            va[p] = sA[((long)sv[p] << stsh) + h];
            vb[p] = sB[((long)sv[p] << stsh) + h];
        }
#pragma unroll
        for (int p = 0; p < PW; p++) {
            xa[p] = *(const half8*)&X0[(long)sv[p] * 128 + cg * 8];
            if (!SX) xb[p] = *(const half8*)&X1[(long)sv[p] * 128 + cg * 8];
        }
        float wa[PW], wb[PW];
#pragma unroll
        for (int p = 0; p < PW; p++) {
            float La = va[p] + sd0, Lb = vb[p] + sd1;
            wa[p] = __expf(fmaxf(La, NEG_SLOPE * La));
            wb[p] = __expf(fmaxf(Lb, NEG_SLOPE * Lb));
            den0 += wa[p];
            den1 += wb[p];
        }
#pragma unroll
        for (int c = 0; c < 8; c++) {
            float a = acc0[c], b = acc1[c];
#pragma unroll
            for (int p = 0; p < PW; p++) {
                a = fmaf(wa[p], (float)xa[p][c], a);
                b = fmaf(wb[p], (float)(SX ? xa[p][c] : xb[p][c]), b);
            }
            acc0[c] = a;
            acc1[c] = b;
        }
    };

    int j = beg;
    if (end - beg >= 2 * PW) {
        int a[PW], b[PW];
#pragma unroll
        for (int p = 0; p < PW; p++) a[p] = cs[j + p];
        while (j + 2 * PW <= end) {
#pragma unroll
            for (int p = 0; p < PW; p++) b[p] = cs[j + PW + p];
            PROC(a);
#pragma unroll
            for (int p = 0; p < PW; p++) a[p] = b[p];
            j += PW;
        }
        PROC(a);
        j += PW;
    }
    for (; j < end; j++) {
        int src = cs[j];
        float va = sA[((long)src << stsh) + h];
        float vb = sB[((long)src << stsh) + h];
        half8 xa = *(const half8*)&X0[(long)src * 128 + cg * 8];
        half8 xb;
        if (!SX) xb = *(const half8*)&X1[(long)src * 128 + cg * 8];
        float La = va + sd0, Lb = vb + sd1;
        float wa = __expf(fmaxf(La, NEG_SLOPE * La));
        float wb = __expf(fmaxf(Lb, NEG_SLOPE * Lb));
        den0 += wa;
        den1 += wb;
#pragma unroll
        for (int c = 0; c < 8; c++) {
            acc0[c] = fmaf(wa, (float)xa[c], acc0[c]);
            acc1[c] = fmaf(wb, (float)(SX ? xa[c] : xb[c]), acc1[c]);
        }
    }

    float inv0 = 1.0f / den0;
    float inv1 = 1.0f / den1;
    half8 oh0, ol0, oh1, ol1;
#pragma unroll
    for (int c = 0; c < 8; c++) {
        float v0 = acc0[c] * inv0;
        half_t h0 = (half_t)v0;
        oh0[c] = h0; ol0[c] = (half_t)(v0 - (float)h0);
        float v1 = acc1[c] * inv1;
        half_t h1 = (half_t)v1;
        oh1[c] = h1; ol1[c] = (half_t)(v1 - (float)h1);
    }
    long yb0 = ((long)(tz * 2) * NNODES + n) * 512 + h * 128 + cg * 8;
    long yb1 = yb0 + (long)NNODES * 512;
    *(half8*)&Yh[yb0] = oh0;
    *(half8*)&Yl[yb0] = ol0;
    *(half8*)&Yh[yb1] = oh1;
    *(half8*)&Yl[yb1] = ol1;
}

// ---------------- split-fp16 MFMA GEMM, instance-strided batch over blockIdx.z ----------
__global__ __launch_bounds__(256) void gemm_b(
    const half_t* __restrict__ Ahb, const half_t* __restrict__ Alb, long aInst,
    const half_t* __restrict__ Bhb, const half_t* __restrict__ Blb, long bInst,
    const float* __restrict__ biasb, long biasInst,
    half_t* __restrict__ Ch, half_t* __restrict__ Cl,
    long cInst, int M, int N, int K) {
    const int i = blockIdx.z;
    const half_t* __restrict__ Ah = Ahb + (long)i * aInst;
    const half_t* __restrict__ Al = Alb + (long)i * aInst;
    const half_t* __restrict__ Bh = Bhb + (long)(i & 1) * bInst;
    const half_t* __restrict__ Bl = Blb + (long)(i & 1) * bInst;
    const float* __restrict__ bias = biasb + (long)(i & 1) * biasInst;

    __shared__ half_t Ash[4 * 128 * 8];
    __shared__ half_t Asl[4 * 128 * 8];
    __shared__ half_t Bsh[4 * 128 * 8];
    __shared__ half_t Bsl[4 * 128 * 8];

    const int tid = threadIdx.x;
    const int row0 = blockIdx.x * 128;
    const int col0 = blockIdx.y * 128;
    const int wave = tid >> 6;
    const int lane = tid & 63;
    const int wm = (wave >> 1) * 64;
    const int wn = (wave & 1) * 64;
    const int chunk = lane >> 4;
    const int l16 = lane & 15;

    floatx4 acc[4][4];
#pragma unroll
    for (int ii = 0; ii < 4; ii++)
#pragma unroll
        for (int j = 0; j < 4; j++) acc[ii][j] = (floatx4)0.0f;

    for (int k0 = 0; k0 < K; k0 += 32) {
        __syncthreads();
#pragma unroll
        for (int p = 0; p < 2; p++) {
            int idx = p * 256 + tid;
            int r = idx >> 2, kc = idx & 3;
            int arow = row0 + r;
            half8 vah, val;
            if (arow < M) {
                vah = *(const half8*)&Ah[(long)arow * K + k0 + kc * 8];
                val = *(const half8*)&Al[(long)arow * K + k0 + kc * 8];
            } else {
#pragma unroll
                for (int q = 0; q < 8; q++) { vah[q] = (half_t)0.f; val[q] = (half_t)0.f; }
            }
            *(half8*)&Ash[(kc * 128 + r) * 8] = vah;
            *(half8*)&Asl[(kc * 128 + r) * 8] = val;
            long boff = (long)(col0 + r) * K + k0 + kc * 8;
            *(half8*)&Bsh[(kc * 128 + r) * 8] = *(const half8*)&Bh[boff];
            *(half8*)&Bsl[(kc * 128 + r) * 8] = *(const half8*)&Bl[boff];
        }
        __syncthreads();
        half8 afh[4], afl[4], bfh[4], bfl[4];
#pragma unroll
        for (int mi = 0; mi < 4; mi++) {
            int o = (chunk * 128 + wm + mi * 16 + l16) * 8;
            afh[mi] = *(const half8*)&Ash[o];
            afl[mi] = *(const half8*)&Asl[o];
        }
#pragma unroll
        for (int ni = 0; ni < 4; ni++) {
            int o = (chunk * 128 + wn + ni * 16 + l16) * 8;
            bfh[ni] = *(const half8*)&Bsh[o];
            bfl[ni] = *(const half8*)&Bsl[o];
        }
#pragma unroll
        for (int mi = 0; mi < 4; mi++)
#pragma unroll
            for (int ni = 0; ni < 4; ni++) {
                acc[mi][ni] = __builtin_amdgcn_mfma_f32_16x16x32_f16(
                    afh[mi], bfh[ni], acc[mi][ni], 0, 0, 0);
                acc[mi][ni] = __builtin_amdgcn_mfma_f32_16x16x32_f16(
                    afh[mi], bfl[ni], acc[mi][ni], 0, 0, 0);
                acc[mi][ni] = __builtin_amdgcn_mfma_f32_16x16x32_f16(
                    afl[mi], bfh[ni], acc[mi][ni], 0, 0, 0);
            }
    }

    // C/D layout: col = lane&15, row = (lane>>4)*4 + reg
    const int r4 = (lane >> 4) * 4;
#pragma unroll
    for (int mi = 0; mi < 4; mi++) {
#pragma unroll
        for (int reg = 0; reg < 4; reg++) {
            int row = row0 + wm + mi * 16 + r4 + reg;
            if (row >= M) continue;
#pragma unroll
            for (int ni = 0; ni < 4; ni++) {
                int col = col0 + wn + ni * 16 + l16;
                float v = fmaxf(acc[mi][ni][reg] + bias[col], 0.f);
                long o = (long)i * cInst + (long)row * N + col;
                half_t hi = (half_t)v;
                Ch[o] = hi;
                Cl[o] = (half_t)(v - (float)hi);
            }
        }
    }
}

// ---------------- fc1 split-K partial: grid (M/128, KS). K-slice per block. ------------
__global__ __launch_bounds__(256) void fc1_part_kernel(
    const half_t* __restrict__ Ah, const half_t* __restrict__ Al,
    const half_t* __restrict__ Bh, const half_t* __restrict__ Bl,
    float* __restrict__ pbuf, int M, int N, int K, int kslice) {
    const int ks = blockIdx.y;
    const int kbeg = ks * kslice;
    const int kend = kbeg + kslice;

    __shared__ half_t Ash[4 * 128 * 8];
    __shared__ half_t Asl[4 * 128 * 8];
    __shared__ half_t Bsh[4 * 128 * 8];
    __shared__ half_t Bsl[4 * 128 * 8];

    const int tid = threadIdx.x;
    const int row0 = blockIdx.x * 128;
    const int wave = tid >> 6;
    const int lane = tid & 63;
    const int wm = (wave >> 1) * 64;
    const int wn = (wave & 1) * 64;
    const int chunk = lane >> 4;
    const int l16 = lane & 15;

    floatx4 acc[4][4];
#pragma unroll
    for (int ii = 0; ii < 4; ii++)
#pragma unroll
        for (int j = 0; j < 4; j++) acc[ii][j] = (floatx4)0.0f;

    for (int k0 = kbeg; k0 < kend; k0 += 32) {
        __syncthreads();
#pragma unroll
        for (int p = 0; p < 2; p++) {
            int idx = p * 256 + tid;
            int r = idx >> 2, kc = idx & 3;
            long aoff = (long)(row0 + r) * K + k0 + kc * 8;
            *(half8*)&Ash[(kc * 128 + r) * 8] = *(const half8*)&Ah[aoff];
            *(half8*)&Asl[(kc * 128 + r) * 8] = *(const half8*)&Al[aoff];
            long boff = (long)r * K + k0 + kc * 8;
            *(half8*)&Bsh[(kc * 128 + r) * 8] = *(const half8*)&Bh[boff];
            *(half8*)&Bsl[(kc * 128 + r) * 8] = *(const half8*)&Bl[boff];
        }
        __syncthreads();
        half8 afh[4], afl[4], bfh[4], bfl[4];
#pragma unroll
        for (int mi = 0; mi < 4; mi++) {
            int o = (chunk * 128 + wm + mi * 16 + l16) * 8;
            afh[mi] = *(const half8*)&Ash[o];
            afl[mi] = *(const half8*)&Asl[o];
        }
#pragma unroll
        for (int ni = 0; ni < 4; ni++) {
            int o = (chunk * 128 + wn + ni * 16 + l16) * 8;
            bfh[ni] = *(const half8*)&Bsh[o];
            bfl[ni] = *(const half8*)&Bsl[o];
        }
#pragma unroll
        for (int mi = 0; mi < 4; mi++)
#pragma unroll
            for (int ni = 0; ni < 4; ni++) {
                acc[mi][ni] = __builtin_amdgcn_mfma_f32_16x16x32_f16(
                    afh[mi], bfh[ni], acc[mi][ni], 0, 0, 0);
                acc[mi][ni] = __builtin_amdgcn_mfma_f32_16x16x32_f16(
                    afh[mi], bfl[ni], acc[mi][ni], 0, 0, 0);
                acc[mi][ni] = __builtin_amdgcn_mfma_f32_16x16x32_f16(
                    afl[mi], bfh[ni], acc[mi][ni], 0, 0, 0);
            }
    }

    const int r4 = (lane >> 4) * 4;
#pragma unroll
    for (int mi = 0; mi < 4; mi++)
#pragma unroll
        for (int reg = 0; reg < 4; reg++) {
            int row = row0 + wm + mi * 16 + r4 + reg;
#pragma unroll
            for (int ni = 0; ni < 4; ni++) {
                int col = wn + ni * 16 + l16;
                pbuf[((long)ks * M + row) * N + col] = acc[mi][ni][reg];
            }
        }
}

// fc1 reduce: h1[i] = relu(sum_ks pbuf[ks][i] + bias[i % N])
__global__ void fc1_reduce_kernel(const float* __restrict__ pbuf, const float* __restrict__ bias,
                                  float* __restrict__ h1, int MN, int KS) {
    int i = blockIdx.x * 256 + threadIdx.x;
    if (i >= MN) return;
    float a = 0.f;
    for (int ks = 0; ks < KS; ks++) a += pbuf[(long)ks * MN + i];
    h1[i] = fmaxf(a + bias[i & (EMB - 1)], 0.f);
}

// ---------------- gather clf_nodes into flat MLP input (reversed timesteps, batched) ------
__global__ void gather_kernel(const half_t* __restrict__ Xh, const half_t* __restrict__ Xl,
                              const int* __restrict__ clf,
                              half_t* __restrict__ flath, half_t* __restrict__ flatl, int t0) {
    int b = blockIdx.x;
    int z = blockIdx.y;
    int tz = blockIdx.z;
    int t = t0 + tz, gz = tz * 2 + z;
    int j = threadIdx.x;  // 64 dwords = 128 halves
    int node = clf[b];
    long dst = (long)b * (TSTEPS * 2 * EMB) + (TSTEPS - 1 - t) * (2 * EMB) + z * EMB;
    long src = ((long)gz * NNODES + node) * EMB;
    ((unsigned int*)&flath[dst])[j] = ((const unsigned int*)&Xh[src])[j];
    ((unsigned int*)&flatl[dst])[j] = ((const unsigned int*)&Xl[src])[j];
}

// ---------------- fc2: [B,128] @ [2,128]^T + bias, relu, fp32 out ----------------
__global__ void fc2_kernel(const float* __restrict__ h1, const float* __restrict__ W,
                           const float* __restrict__ bias, float* __restrict__ out) {
    int row = blockIdx.x;
    int lane = threadIdx.x;  // 64
    float x0 = h1[(long)row * 128 + lane];
    float x1 = h1[(long)row * 128 + 64 + lane];
    float p0 = x0 * W[lane] + x1 * W[64 + lane];
    float p1 = x0 * W[128 + lane] + x1 * W[192 + lane];
    for (int off = 32; off; off >>= 1) {
        p0 += __shfl_down(p0, off);
        p1 += __shfl_down(p1, off);
    }
    if (lane == 0) {
        out[row * 2 + 0] = fmaxf(p0 + bias[0], 0.f);
        out[row * 2 + 1] = fmaxf(p1 + bias[1], 0.f);
    }
}

extern "C" void kernel_launch(void* const* d_in, const int* in_sizes, int n_in,
                              void* d_out, int out_size, void* d_ws, size_t ws_size,
                              hipStream_t stream) {
    const float* emb     = (const float*)d_in[0];
    const int*   edges   = (const int*)d_in[1];
    const int*   clf     = (const int*)d_in[5];
    const float* gat_W1  = (const float*)d_in[6];
    const float* gat_as1 = (const float*)d_in[7];
    const float* gat_ad1 = (const float*)d_in[8];
    const float* gat_b1  = (const float*)d_in[9];
    const float* lin_W1  = (const float*)d_in[10];
    const float* lin_b1  = (const float*)d_in[11];
    const float* gat_W2  = (const float*)d_in[12];
    const float* gat_as2 = (const float*)d_in[13];
    const float* gat_ad2 = (const float*)d_in[14];
    const float* gat_b2  = (const float*)d_in[15];
    const float* lin_W2  = (const float*)d_in[16];
    const float* lin_b2  = (const float*)d_in[17];
    const float* fc1_W   = (const float*)d_in[18];
    const float* fc1_b   = (const float*)d_in[19];
    const float* fc2_W   = (const float*)d_in[20];
    const float* fc2_b   = (const float*)d_in[21];
    float* out = (float*)d_out;

    char* ws = (char*)d_ws;
    size_t off = 0;
    auto alloc = [&](size_t bytes) -> char* {
        char* p = ws + off;
        off += (bytes + 255) & ~(size_t)255;
        return p;
    };
    // ---- fixed, both-phase allocations ----
    int* counts  = (int*)alloc((size_t)TSTEPS * NNODES * 4);
    int* rowptr  = (int*)alloc((size_t)TSTEPS * (NNODES + 1) * 4);
    int* csr_src = (int*)alloc((size_t)TSTEPS * ETOT * 4);
    int* bsum    = (int*)alloc((size_t)TSTEPS * NSCHUNK * 4);
    int* boff    = (int*)alloc((size_t)TSTEPS * NSCHUNK * 4);
    int* bcnt    = (int*)alloc((size_t)TSTEPS * NSB * 4);
    half_t* embh = (half_t*)alloc((size_t)TSTEPS * NNODES * EMB * 2);
    half_t* Mh   = (half_t*)alloc((size_t)4 * EMB * HC * 2);
    half_t* Ml   = (half_t*)alloc((size_t)4 * EMB * HC * 2);
    float*  cb   = (float*)alloc((size_t)4 * EMB * 4);
    half_t* fc1Wh = (half_t*)alloc((size_t)EMB * 2 * EMB * TSTEPS * 2);
    half_t* fc1Wl = (half_t*)alloc((size_t)EMB * 2 * EMB * TSTEPS * 2);
    float* wasb = (float*)alloc((size_t)2 * 2 * 4 * 128 * 4);
    float* wadb = (float*)alloc((size_t)2 * 2 * 4 * 128 * 4);
    half_t* WS0h = (half_t*)alloc((size_t)16 * 128 * 2);
    half_t* WS0l = (half_t*)alloc((size_t)16 * 128 * 2);
    half_t* WS1h = (half_t*)alloc((size_t)2 * 16 * 128 * 2);
    half_t* WS1l = (half_t*)alloc((size_t)2 * 16 * 128 * 2);
    float* s0buf = (float*)alloc((size_t)TSTEPS * NNODES * 16 * 4);   // [t][n][16]
    half_t* flath = (half_t*)alloc((size_t)BCLF * (TSTEPS * 2 * EMB) * 2);
    half_t* flatl = (half_t*)alloc((size_t)BCLF * (TSTEPS * 2 * EMB) * 2);
    float* h1buf = (float*)alloc((size_t)BCLF * EMB * 4);

    // ---- phase-overlapped region: {embl, pairs} (pre-loop) aliases loop buffers ----
    size_t region_base = off;
    half_t* embl = (half_t*)alloc((size_t)TSTEPS * NNODES * EMB * 2);
    int* pairs   = (int*)alloc((size_t)TSTEPS * NSB * PCAP * 4);

    // per-timestep loop footprint: Yh+Yl + Xh+Xl + s1
    const size_t perT = ((size_t)2 * NNODES * HC * 2 * 2) +      // Yh+Yl
                        ((size_t)2 * NNODES * EMB * 2 * 2) +     // Xh+Xl
                        ((size_t)NNODES * 16 * 4) + 2048;        // s1 + align slop
    int TG = 1;
    if (ws_size > region_base + perT) {
        size_t cap = (ws_size - region_base) / perT;
        TG = (cap >= 10) ? 10 : (int)cap;
        if (TG < 1) TG = 1;
    }
    off = region_base;  // loop-phase buffers alias embl/pairs
    half_t* Yh = (half_t*)alloc((size_t)TG * 2 * NNODES * HC * 2);
    half_t* Yl = (half_t*)alloc((size_t)TG * 2 * NNODES * HC * 2);
    half_t* Xh = (half_t*)alloc((size_t)TG * 2 * NNODES * EMB * 2);
    half_t* Xl = (half_t*)alloc((size_t)TG * 2 * NNODES * EMB * 2);
    float* s1buf = (float*)alloc((size_t)TG * NNODES * 16 * 4);   // [tz][n][16]

    // ---- conversions + fused-weight precompute ----
    {
        long n4 = (long)TSTEPS * NNODES * EMB / 4;
        cvt_split_kernel<<<(int)((n4 + 255) / 256), 256, 0, stream>>>(emb, embh, embl, n4);
        long f4 = (long)EMB * 2 * EMB * TSTEPS / 4;
        cvt_split_kernel<<<(int)((f4 + 255) / 256), 256, 0, stream>>>(fc1_W, fc1Wh, fc1Wl, f4);
    }
    prep_was_kernel<<<16, 128, 0, stream>>>(gat_W1, gat_W2, gat_as1, gat_as2,
                                            gat_ad1, gat_ad2, wasb, wadb);
    pack_ws_kernel<<<48, 128, 0, stream>>>(wasb, wadb, WS0h, WS0l, WS1h, WS1l);
    prep_M_kernel<<<dim3(128, 4), 128, 0, stream>>>(gat_W1, gat_W2, lin_W1, lin_W2, Mh, Ml);
    prep_cb_kernel<<<4, 128, 0, stream>>>(lin_W1, lin_W2, gat_b1, gat_b2, lin_b1, lin_b2, cb);

    // layer-0 scores for all timesteps, both z: [200000,128]@[128,16] (uses embl)
    scores_b<<<dim3(3125, 1), 256, 0, stream>>>(
        embh, embl, 0, WS0h, WS0l, 0, 0, s0buf, 0, 0, TSTEPS * NNODES, 16, 16);

    // ---- CSR build: partition -> count -> scan -> staged fill ----
    hipMemsetAsync(bcnt, 0, (size_t)TSTEPS * NSB * 4, stream);
    part64_kernel<<<dim3(NCHUNKS, TSTEPS), 256, 0, stream>>>(edges, bcnt, pairs);
    count_sb_kernel<<<NSB * TSTEPS, 256, 0, stream>>>(pairs, bcnt, counts);
    scanA_kernel<<<TSTEPS * NSCHUNK, 256, 0, stream>>>(counts, bsum);
    scanB_kernel<<<TSTEPS, 128, 0, stream>>>(bsum, boff, rowptr);
    scanC_kernel<<<TSTEPS * NSCHUNK, 256, 0, stream>>>(counts, boff, rowptr);
    fill_sb_kernel<<<NSB * TSTEPS, 256, 0, stream>>>(pairs, bcnt, rowptr, csr_src);
    // (pairs/embl dead from here on; loop-phase buffers may overwrite them)

    for (int t0 = 0; t0 < TSTEPS; t0 += TG) {
        int tg = (TSTEPS - t0 < TG) ? (TSTEPS - t0) : TG;
        // ---- layer 0: z-fused aggregation (shared X = embeddings), 4-wide ----
        agg2_kernel<true, 4><<<dim3(5000, tg), 256, 0, stream>>>(
            embh + (long)t0 * NNODES * EMB, nullptr, (long)NNODES * EMB,
            s0buf + (long)t0 * NNODES * 16, s0buf + (long)t0 * NNODES * 16 + 8,
            4, (long)NNODES * 16,
            rowptr, csr_src, Yh, Yl, t0);
        gemm_b<<<dim3(157, 1, 2 * tg), 256, 0, stream>>>(
            Yh, Yl, (long)NNODES * HC,
            Mh, Ml, (long)EMB * HC, cb, EMB,
            Xh, Xl, (long)NNODES * EMB, NNODES, EMB, HC);
        // layer-1 scores -> [tz][n][16] rows (z0 cols 0-7, z1 cols 8-15)
        scores_b<<<dim3(313, 2 * tg), 256, 0, stream>>>(
            Xh, Xl, (long)NNODES * EMB,
            WS1h, WS1l, (long)16 * 128, 1,
            s1buf, (long)NNODES * 16, 8, NNODES, 16, 8);
        // ---- layer 1: z-fused aggregation (per-z X), 2-wide ----
        agg2_kernel<false, 2><<<dim3(5000, tg), 256, 0, stream>>>(
            Xh, Xh + (long)NNODES * EMB, (long)2 * NNODES * EMB,
            s1buf, s1buf + 8, 4, (long)NNODES * 16,
            rowptr, csr_src, Yh, Yl, t0);
        gemm_b<<<dim3(157, 1, 2 * tg), 256, 0, stream>>>(
            Yh, Yl, (long)NNODES * HC,
            Mh + (long)2 * EMB * HC, Ml + (long)2 * EMB * HC, (long)EMB * HC,
            cb + 2 * EMB, EMB,
            Xh, Xl, (long)NNODES * EMB, NNODES, EMB, HC);
        gather_kernel<<<dim3(BCLF, 2, tg), 64, 0, stream>>>(Xh, Xl, clf, flath, flatl, t0);
    }
    // ---- head MLP: split-K fc1 (partials aliased onto dead Y region) + reduce + fc2 ----
    float* pbuf = (float*)Yh;   // 8 * 4096 * 128 * 4 = 16.8 MB << Y region
    fc1_part_kernel<<<dim3(32, 8), 256, 0, stream>>>(
        flath, flatl, fc1Wh, fc1Wl, pbuf, BCLF, EMB, TSTEPS * 2 * EMB, (TSTEPS * 2 * EMB) / 8);
    fc1_reduce_kernel<<<(BCLF * EMB + 255) / 256, 256, 0, stream>>>(
        pbuf, fc1_b, h1buf, BCLF * EMB, 8);
    fc2_kernel<<<BCLF, 64, 0, stream>>>(h1buf, fc2_W, fc2_b, out);
}